// Round 14
// baseline (44.058 us; speedup 1.0000x reference)
//
#include <hip/hip_runtime.h>

typedef __bf16 bf16_t;
typedef __bf16 bf16x4 __attribute__((ext_vector_type(4)));
typedef __bf16 bf16x8 __attribute__((ext_vector_type(8)));
typedef float  f32x4  __attribute__((ext_vector_type(4)));

#define B_SZ  16
#define L_SEQ 2048
#define D_H   64
#define QB    128
#define KB    128
#define NT128 16                 // L_SEQ / KB
#define TILE_HW (KB * D_H)       // 8192 bf16 per tile image (16 KB)
#define IMG_ELEMS ((size_t)B_SZ * NT128 * TILE_HW)   // per tensor

// softmax is over (S/8); fold log2(e)/8 into Q so MFMA output is in log2 units
#define QSCALE 0.18033688011112043f

#define GLD_LDS16(g, l) __builtin_amdgcn_global_load_lds(                       \
    (const __attribute__((address_space(1))) void*)(g),                         \
    (__attribute__((address_space(3))) void*)(l), 16, 0, 0)

// ---------------- preproc: bf16 + transpose(V) + XOR-swizzle baked into ws images ----
__global__ __launch_bounds__(256)
void preproc_kernel(const float* __restrict__ Kg, const float* __restrict__ Vg,
                    bf16_t* __restrict__ Kimg, bf16_t* __restrict__ Vimg)
{
    const int kt = blockIdx.x, b = blockIdx.y, z = blockIdx.z;   // z = quarter
    const int t  = threadIdx.x;
    const size_t src = (size_t)b * L_SEQ * D_H + (size_t)kt * KB * D_H;
    bf16_t* ko = Kimg + (size_t)(b * NT128 + kt) * TILE_HW;
    bf16_t* vo = Vimg + (size_t)(b * NT128 + kt) * TILE_HW;

    {
        const int u = z * 256 + t, r = u >> 3, ch = u & 7;
        const float* p = Kg + src + r * 64 + ch * 8;
        const f32x4 a = *reinterpret_cast<const f32x4*>(p);
        const f32x4 c = *reinterpret_cast<const f32x4*>(p + 4);
        bf16x8 kk;
#pragma unroll
        for (int j = 0; j < 4; ++j) { kk[j] = (bf16_t)a[j]; kk[4 + j] = (bf16_t)c[j]; }
        *reinterpret_cast<bf16x8*>(&ko[r * 64 + ((ch ^ (r & 7)) << 3)]) = kk;
    }
    {
        const int d = t & 63, pc = (t >> 6) + z * 4;
        bf16x8 vv;
#pragma unroll
        for (int pw = 0; pw < 8; ++pw) {
            const int pos = pc * 8 + pw;
            const int vkb = ((pos >> 3) & 3) | (((pos >> 2) & 1) << 2) | (((pos >> 5) & 3) << 3);
            const int k   = (vkb << 2) | (pos & 3);
            vv[pw] = (bf16_t)Vg[src + (size_t)k * 64 + d];
        }
        *reinterpret_cast<bf16x8*>(&vo[d * 128 + ((pc ^ (d & 7)) << 3)]) = vv;
    }
}

// ---------------- main kernel: 4-wave engine, 32 q per wave, 4-way K-split, 2 blocks/CU ----
// Each ds_read of K/V^T feeds TWO MFMAs (q-groups g=0,1) -> LDS bytes per S-cell halved.
__global__ __launch_bounds__(256, 2)
void attn_split4_kernel(const float* __restrict__ Qg, float* __restrict__ Og,
                        const bf16_t* __restrict__ Kimg, const bf16_t* __restrict__ Vimg,
                        float* __restrict__ Opart, float* __restrict__ MLb)
{
    const int lin  = blockIdx.x;          // 0..511
    const int xcd  = lin & 7;
    const int b    = xcd * 2 + ((lin >> 3) & 1);
    const int p    = (lin >> 4) & 7;
    const int role = (lin >> 7) & 3;
    const int pair = b * 8 + p;

    const int nktL = 16 - p;
    const int posStart = (role == 0) ? 0 : (role == 1) ? 5 : (role == 2) ? 9 : 13;
    const int total    = (role == 0) ? 5 : 4;
    int cnt1 = nktL - posStart;
    cnt1 = cnt1 < 0 ? 0 : (cnt1 > total ? total : cnt1);   // this role's tileL iters

    const int slotL = (pair * 4 + role) * 2;
    const int slotS = slotL + 1;

    const int tid  = threadIdx.x;
    const int wave = tid >> 6;             // 0..3
    const int lane = tid & 63;
    const int lg   = lane >> 4;
    const int lc   = lane & 15;
    const int lc7  = lc & 7;

    __shared__ __align__(16) bf16_t K_lds[2][TILE_HW];    // 32 KB
    __shared__ __align__(16) bf16_t Vt_lds[2][TILE_HW];   // 32 KB

    const size_t bbase = (size_t)b * L_SEQ * D_H;
    const bf16_t* kimg = Kimg + (size_t)b * NT128 * TILE_HW;
    const bf16_t* vimg = Vimg + (size_t)b * NT128 * TILE_HW;

    auto posToKt = [&](int j) { const int pos = posStart + j; return pos < nktL ? pos : pos - nktL; };

    auto stage = [&](int kt, int buf) {
        const bf16_t* ks = kimg + (size_t)kt * TILE_HW;
        const bf16_t* vs = vimg + (size_t)kt * TILE_HW;
#pragma unroll
        for (int i = 0; i < 4; ++i) {
            const int c = wave * 4 + i;                    // chunk 0..15 (512 bf16)
            GLD_LDS16(ks + c * 512 + lane * 8, &K_lds[buf][c * 512]);
            GLD_LDS16(vs + c * 512 + lane * 8, &Vt_lds[buf][c * 512]);
        }
    };

    bf16x8 qa[2][2];     // [q-group][h]
    int qrow0;
    auto loadQ = [&](int qt_) {
        qrow0 = qt_ * QB + wave * 32 + lc;
#pragma unroll
        for (int g = 0; g < 2; ++g)
#pragma unroll
            for (int h = 0; h < 2; ++h) {
                const float* qp = Qg + bbase + (size_t)(qrow0 + g * 16) * D_H + h * 32 + lg * 8;
                const f32x4 f0 = *reinterpret_cast<const f32x4*>(qp);
                const f32x4 f1 = *reinterpret_cast<const f32x4*>(qp + 4);
                bf16x8 a;
#pragma unroll
                for (int j = 0; j < 4; ++j) { a[j] = (bf16_t)(f0[j] * QSCALE); a[4 + j] = (bf16_t)(f1[j] * QSCALE); }
                qa[g][h] = a;
            }
    };

    int qt = (cnt1 > 0) ? (15 - p) : p;
    loadQ(qt);

    f32x4 o[2][4];
    float m[2], l[2];
#pragma unroll
    for (int g = 0; g < 2; ++g) {
#pragma unroll
        for (int dt = 0; dt < 4; ++dt) o[g][dt] = (f32x4){0.f, 0.f, 0.f, 0.f};
        m[g] = -1e30f; l[g] = 0.f;
    }

    auto writePartial = [&](int slot) {
        float* ob = Opart + (size_t)slot * (QB * D_H);
#pragma unroll
        for (int g = 0; g < 2; ++g) {
            float lr = l[g];
            lr += __shfl_xor(lr, 16);
            lr += __shfl_xor(lr, 32);
            const int qL = wave * 32 + g * 16 + lc;   // 0..127
#pragma unroll
            for (int dt = 0; dt < 4; ++dt)
                *reinterpret_cast<f32x4*>(&ob[qL * 64 + dt * 16 + lg * 4]) = o[g][dt];
            if (lg == 0) { MLb[slot * 256 + qL] = m[g]; MLb[slot * 256 + 128 + qL] = lr; }
        }
    };
    auto writeEmpty = [&](int slot) {
#pragma unroll
        for (int g = 0; g < 2; ++g) {
            const int qL = wave * 32 + g * 16 + lc;
            if (lg == 0) { MLb[slot * 256 + qL] = -1e30f; MLb[slot * 256 + 128 + qL] = 0.f; }
        }
    };

    stage(posToKt(0), 0);
    __syncthreads();
    int cur = 0;

    for (int j = 0; j < total; ++j) {
        if (cnt1 > 0 && cnt1 < total && j == cnt1) {
            // straddler: commit tileL partial, switch to tileS
            writePartial(slotL);
            qt = p; loadQ(qt);
#pragma unroll
            for (int g = 0; g < 2; ++g) {
#pragma unroll
                for (int dt = 0; dt < 4; ++dt) o[g][dt] = (f32x4){0.f, 0.f, 0.f, 0.f};
                m[g] = -1e30f; l[g] = 0.f;
            }
        }
        const int pos = posStart + j;
        const int kt  = pos < nktL ? pos : pos - nktL;
        const int kb0 = kt * KB;
        if (j + 1 < total) stage(posToKt(j + 1), cur ^ 1);   // prefetch (q-independent)

        // ---- S^T = K Q^T: one kb read feeds both q-groups ----
        f32x4 sc[2][8];
        __builtin_amdgcn_s_setprio(1);
#pragma unroll
        for (int n = 0; n < 8; ++n) {
            f32x4 a0 = (f32x4){0.f, 0.f, 0.f, 0.f};
            f32x4 a1 = (f32x4){0.f, 0.f, 0.f, 0.f};
#pragma unroll
            for (int h = 0; h < 2; ++h) {
                const int hw = (n * 16 + lc) * 64 + ((((h << 2) | lg) ^ lc7) << 3);
                const bf16x8 kkb = *reinterpret_cast<const bf16x8*>(&K_lds[cur][hw]);
                a0 = __builtin_amdgcn_mfma_f32_16x16x32_bf16(kkb, qa[0][h], a0, 0, 0, 0);
                a1 = __builtin_amdgcn_mfma_f32_16x16x32_bf16(kkb, qa[1][h], a1, 0, 0, 0);
            }
            sc[0][n] = a0; sc[1][n] = a1;
        }
        __builtin_amdgcn_s_setprio(0);

        const bool diag = (pos == nktL - 1) || (pos == 16);  // diagonal tile of L or S
        if (diag) {
#pragma unroll
            for (int g = 0; g < 2; ++g) {
                const int qr = qrow0 + g * 16;
#pragma unroll
                for (int n = 0; n < 8; ++n)
#pragma unroll
                    for (int r = 0; r < 4; ++r)
                        if (kb0 + n * 16 + lg * 4 + r > qr) sc[g][n][r] = -1e30f;
            }
        }

        // ---- defer-max online softmax, independent per q-group ----
        bf16x8 w[2][4];
#pragma unroll
        for (int g = 0; g < 2; ++g) {
            float mxp = fmaxf(fmaxf(sc[g][0][0], sc[g][0][1]), fmaxf(sc[g][0][2], sc[g][0][3]));
#pragma unroll
            for (int n = 1; n < 8; ++n)
                mxp = fmaxf(mxp, fmaxf(fmaxf(sc[g][n][0], sc[g][n][1]), fmaxf(sc[g][n][2], sc[g][n][3])));
            if (!__all(mxp <= m[g] + 8.0f)) {
                float mx = mxp;
                mx = fmaxf(mx, __shfl_xor(mx, 16));
                mx = fmaxf(mx, __shfl_xor(mx, 32));
                const float mn = fmaxf(m[g], mx);
                const float alpha = exp2f(m[g] - mn);
                m[g] = mn;
                l[g] *= alpha;
#pragma unroll
                for (int dt = 0; dt < 4; ++dt)
#pragma unroll
                    for (int r = 0; r < 4; ++r) o[g][dt][r] *= alpha;
            }
            float rs = 0.f;
#pragma unroll
            for (int n = 0; n < 8; ++n) {
                const float p0 = exp2f(sc[g][n][0] - m[g]), p1 = exp2f(sc[g][n][1] - m[g]);
                const float p2 = exp2f(sc[g][n][2] - m[g]), p3 = exp2f(sc[g][n][3] - m[g]);
                rs += (p0 + p1) + (p2 + p3);
                const int wi = n >> 1, off = (n & 1) * 4;
                w[g][wi][off + 0] = (bf16_t)p0; w[g][wi][off + 1] = (bf16_t)p1;
                w[g][wi][off + 2] = (bf16_t)p2; w[g][wi][off + 3] = (bf16_t)p3;
            }
            l[g] += rs;
        }

        // ---- O^T += V^T P : one vb read feeds both q-groups ----
        __builtin_amdgcn_s_setprio(1);
#pragma unroll
        for (int ks = 0; ks < 4; ++ks) {
#pragma unroll
            for (int dt = 0; dt < 4; ++dt) {
                const int hw = (dt * 16 + lc) * 128 + ((((ks << 2) | lg) ^ lc7) << 3);
                const bf16x8 vb = *reinterpret_cast<const bf16x8*>(&Vt_lds[cur][hw]);
                o[0][dt] = __builtin_amdgcn_mfma_f32_16x16x32_bf16(vb, w[0][ks], o[0][dt], 0, 0, 0);
                o[1][dt] = __builtin_amdgcn_mfma_f32_16x16x32_bf16(vb, w[1][ks], o[1][dt], 0, 0, 0);
            }
        }
        __builtin_amdgcn_s_setprio(0);

        __syncthreads();   // prefetched stage landed; cur free
        cur ^= 1;
    }

    // ---- epilogue: commit final partial; mark untouched tile type empty ----
    if (cnt1 == total) {
        writePartial(slotL);
        writeEmpty(slotS);
    } else if (cnt1 == 0) {
        writeEmpty(slotL);
        writePartial(slotS);
    } else {
        writePartial(slotS);
    }
}

// ---------------- merge: combine up to 4 partials per (pair, tile-type) ----------------
__global__ __launch_bounds__(256)
void merge4_kernel(const float* __restrict__ Opart, const float* __restrict__ MLb,
                   float* __restrict__ Og)
{
    const int blk     = blockIdx.x;       // 0..511
    const int tileIdx = blk >> 1;         // 0..255
    const int sub     = blk & 1;
    const int pair    = tileIdx >> 1;     // 0..127
    const int type    = tileIdx & 1;      // 0 = tileL, 1 = tileS
    const int b  = pair >> 3, p = pair & 7;
    const int qt = type ? p : (15 - p);
    const int t  = threadIdx.x;
    const int q  = sub * 64 + (t >> 2);   // 0..127
    const int dc = (t & 3) * 16;          // 0,16,32,48

    float mv[4], lv[4];
#pragma unroll
    for (int r = 0; r < 4; ++r) {
        const int slot = (pair * 4 + r) * 2 + type;
        mv[r] = MLb[slot * 256 + q];
        lv[r] = MLb[slot * 256 + 128 + q];
    }
    const float mt = fmaxf(fmaxf(mv[0], mv[1]), fmaxf(mv[2], mv[3]));
    float wv[4], den = 0.f;
#pragma unroll
    for (int r = 0; r < 4; ++r) { wv[r] = exp2f(mv[r] - mt); den += lv[r] * wv[r]; }
    const float inv = 1.0f / den;

    f32x4 acc[4];
#pragma unroll
    for (int i = 0; i < 4; ++i) acc[i] = (f32x4){0.f, 0.f, 0.f, 0.f};
#pragma unroll
    for (int r = 0; r < 4; ++r) {
        if (lv[r] != 0.0f) {              // empty slots skipped
            const float* orp = Opart + (size_t)((pair * 4 + r) * 2 + type) * (QB * D_H) + q * 64 + dc;
#pragma unroll
            for (int i = 0; i < 4; ++i) {
                const f32x4 v = *reinterpret_cast<const f32x4*>(orp + i * 4);
#pragma unroll
                for (int k2 = 0; k2 < 4; ++k2) acc[i][k2] += v[k2] * wv[r];
            }
        }
    }
    float* og = Og + (size_t)b * L_SEQ * D_H + (size_t)(qt * QB + q) * D_H + dc;
#pragma unroll
    for (int i = 0; i < 4; ++i) {
        f32x4 rr;
#pragma unroll
        for (int k2 = 0; k2 < 4; ++k2) rr[k2] = acc[i][k2] * inv;
        *reinterpret_cast<f32x4*>(og + i * 4) = rr;
    }
}

// ---------------- fallback (no-ws path, round-6 kernel) ----------------
__global__ __launch_bounds__(256, 2)
void attn_fwd_fb(const float* __restrict__ Qg, const float* __restrict__ Kg,
                 const float* __restrict__ Vg, float* __restrict__ Og)
{
    const int lin  = blockIdx.x;
    const int xcd  = lin & 7;
    const int slot = lin >> 3;
    const int half = slot >> 5;
    const int qi   = slot & 31;
    const int b    = xcd * 2 + half;
    const int qt   = half ? qi : (31 - qi);

    const int tid  = threadIdx.x;
    const int lane = tid & 63;
    const int lg   = lane >> 4;
    const int lc   = lane & 15;
    const int lc7  = lc & 7;

    __shared__ __align__(16) bf16_t K_lds[2][KB * D_H];
    __shared__ __align__(16) bf16_t Vt_lds[2][D_H * KB];

    const size_t bbase = (size_t)b * L_SEQ * D_H;
    const int qrow = qt * 64 + (tid >> 6) * 16 + lc;
    bf16x8 qa[2];
#pragma unroll
    for (int h = 0; h < 2; ++h) {
        const float* qp = Qg + bbase + (size_t)qrow * D_H + h * 32 + lg * 8;
        const f32x4 f0 = *reinterpret_cast<const f32x4*>(qp);
        const f32x4 f1 = *reinterpret_cast<const f32x4*>(qp + 4);
        bf16x8 a;
#pragma unroll
        for (int j = 0; j < 4; ++j) { a[j] = (bf16_t)(f0[j] * QSCALE); a[4 + j] = (bf16_t)(f1[j] * QSCALE); }
        qa[h] = a;
    }
    f32x4 o[4];
#pragma unroll
    for (int dt = 0; dt < 4; ++dt) o[dt] = (f32x4){0.f, 0.f, 0.f, 0.f};
    float m = -1e30f, l = 0.f;
    const int nkt = (qt + 2) >> 1;
    const int vkb  = tid & 31;
    const int vdg  = tid >> 5;
    const int vpos = ((vkb >> 3) << 5) + ((vkb & 3) << 3) + (((vkb >> 2) & 1) << 2);
    f32x4 kreg[8], vreg[8];

    auto issueK = [&](int kt) {
        const int kbase = kt * KB;
#pragma unroll
        for (int i = 0; i < 4; ++i) {
            const int u = i * 256 + tid;
            const int r = u >> 3, ch = u & 7;
            const float* p = Kg + bbase + (size_t)(kbase + r) * D_H + ch * 8;
            kreg[2 * i]     = *reinterpret_cast<const f32x4*>(p);
            kreg[2 * i + 1] = *reinterpret_cast<const f32x4*>(p + 4);
        }
    };
    auto issueV = [&](int kt) {
        const int kbase = kt * KB;
#pragma unroll
        for (int d2 = 0; d2 < 2; ++d2)
#pragma unroll
            for (int i = 0; i < 4; ++i)
                vreg[d2 * 4 + i] = *reinterpret_cast<const f32x4*>(
                    Vg + bbase + (size_t)(kbase + vkb * 4 + i) * D_H + (vdg + d2 * 8) * 4);
    };
    auto writeK = [&](int buf) {
#pragma unroll
        for (int i = 0; i < 4; ++i) {
            const int u = i * 256 + tid;
            const int r = u >> 3, ch = u & 7;
            bf16x8 kk;
#pragma unroll
            for (int j = 0; j < 4; ++j) { kk[j] = (bf16_t)kreg[2 * i][j]; kk[4 + j] = (bf16_t)kreg[2 * i + 1][j]; }
            *reinterpret_cast<bf16x8*>(&K_lds[buf][r * 64 + ((ch ^ (r & 7)) << 3)]) = kk;
        }
    };
    auto writeV = [&](int buf) {
#pragma unroll
        for (int d2 = 0; d2 < 2; ++d2) {
            const int db = vdg + d2 * 8;
#pragma unroll
            for (int j = 0; j < 4; ++j) {
                const int d = db * 4 + j;
                bf16x4 cj = { (bf16_t)vreg[d2 * 4 + 0][j], (bf16_t)vreg[d2 * 4 + 1][j],
                              (bf16_t)vreg[d2 * 4 + 2][j], (bf16_t)vreg[d2 * 4 + 3][j] };
                const int hw = d * 128 + (((vpos >> 3) ^ (d & 7)) << 3) + (vpos & 7);
                *reinterpret_cast<bf16x4*>(&Vt_lds[buf][hw]) = cj;
            }
        }
    };

    issueK(0); issueV(0); writeK(0); writeV(0);
    __syncthreads();
    int cur = 0;
    for (int kt = 0; kt < nkt; ++kt) {
        const bool last = (kt == nkt - 1);
        const int kbase = kt * KB;
        if (!last) issueK(kt + 1);
        f32x4 sc[8];
#pragma unroll
        for (int n = 0; n < 8; ++n) {
            f32x4 acc = (f32x4){0.f, 0.f, 0.f, 0.f};
#pragma unroll
            for (int h = 0; h < 2; ++h) {
                const int hw = (n * 16 + lc) * 64 + ((((h << 2) | lg) ^ lc7) << 3);
                const bf16x8 kkb = *reinterpret_cast<const bf16x8*>(&K_lds[cur][hw]);
                acc = __builtin_amdgcn_mfma_f32_16x16x32_bf16(kkb, qa[h], acc, 0, 0, 0);
            }
            sc[n] = acc;
        }
        if (!last) issueV(kt + 1);
        if (last) {
#pragma unroll
            for (int n = 0; n < 8; ++n)
#pragma unroll
                for (int r = 0; r < 4; ++r)
                    if (kbase + n * 16 + lg * 4 + r > qrow) sc[n][r] = -1e30f;
        }
        float mxp = fmaxf(fmaxf(sc[0][0], sc[0][1]), fmaxf(sc[0][2], sc[0][3]));
#pragma unroll
        for (int n = 1; n < 8; ++n)
            mxp = fmaxf(mxp, fmaxf(fmaxf(sc[n][0], sc[n][1]), fmaxf(sc[n][2], sc[n][3])));
        if (!__all(mxp <= m + 8.0f)) {
            float mx = mxp;
            mx = fmaxf(mx, __shfl_xor(mx, 16));
            mx = fmaxf(mx, __shfl_xor(mx, 32));
            const float mn = fmaxf(m, mx);
            const float alpha = exp2f(m - mn);
            m = mn; l *= alpha;
#pragma unroll
            for (int dt = 0; dt < 4; ++dt)
#pragma unroll
                for (int r = 0; r < 4; ++r) o[dt][r] *= alpha;
        }
        bf16x8 w[4];
        float rs = 0.f;
#pragma unroll
        for (int n = 0; n < 8; ++n) {
            const float p0 = exp2f(sc[n][0] - m), p1 = exp2f(sc[n][1] - m);
            const float p2 = exp2f(sc[n][2] - m), p3 = exp2f(sc[n][3] - m);
            rs += (p0 + p1) + (p2 + p3);
            const int wi = n >> 1, off = (n & 1) * 4;
            w[wi][off + 0] = (bf16_t)p0; w[wi][off + 1] = (bf16_t)p1;
            w[wi][off + 2] = (bf16_t)p2; w[wi][off + 3] = (bf16_t)p3;
        }
        l += rs;
        if (!last) writeK(cur ^ 1);
#pragma unroll
        for (int ks = 0; ks < 4; ++ks) {
#pragma unroll
            for (int dt = 0; dt < 4; ++dt) {
                const int hw = (dt * 16 + lc) * 128 + ((((ks << 2) | lg) ^ lc7) << 3);
                const bf16x8 vb = *reinterpret_cast<const bf16x8*>(&Vt_lds[cur][hw]);
                o[dt] = __builtin_amdgcn_mfma_f32_16x16x32_bf16(vb, w[ks], o[dt], 0, 0, 0);
            }
        }
        if (!last) writeV(cur ^ 1);
        __syncthreads();
        cur ^= 1;
    }
    float lr = l;
    lr += __shfl_xor(lr, 16);
    lr += __shfl_xor(lr, 32);
    const float inv = 1.0f / lr;
#pragma unroll
    for (int dt = 0; dt < 4; ++dt) {
        f32x4 val = { o[dt][0] * inv, o[dt][1] * inv, o[dt][2] * inv, o[dt][3] * inv };
        *reinterpret_cast<f32x4*>(Og + bbase + (size_t)qrow * D_H + dt * 16 + lg * 4) = val;
    }
}

extern "C" void kernel_launch(void* const* d_in, const int* in_sizes, int n_in,
                              void* d_out, int out_size, void* d_ws, size_t ws_size,
                              hipStream_t stream)
{
    const float* Q = (const float*)d_in[0];
    const float* K = (const float*)d_in[1];
    const float* V = (const float*)d_in[2];
    float* O = (float*)d_out;

    const size_t img_bytes = 2 * IMG_ELEMS * sizeof(bf16_t);              // 8 MB
    const size_t opart_fl  = (size_t)1024 * (QB * D_H);                   // 8M floats (32 MB)
    const size_t ml_fl     = (size_t)1024 * 256;                          // 256K floats (1 MB)
    const size_t need = img_bytes + (opart_fl + ml_fl) * sizeof(float);   // ~41 MB

    if (ws_size >= need) {
        bf16_t* Kimg  = (bf16_t*)d_ws;
        bf16_t* Vimg  = Kimg + IMG_ELEMS;
        float*  Opart = (float*)((char*)d_ws + img_bytes);
        float*  MLb   = Opart + opart_fl;
        preproc_kernel<<<dim3(NT128, B_SZ, 4), dim3(256), 0, stream>>>(K, V, Kimg, Vimg);
        attn_split4_kernel<<<dim3(512), dim3(256), 0, stream>>>(Q, O, Kimg, Vimg, Opart, MLb);
        merge4_kernel<<<dim3(512), dim3(256), 0, stream>>>(Opart, MLb, O);
    } else {
        attn_fwd_fb<<<dim3(512), dim3(256), 0, stream>>>(Q, K, V, O);
    }
}

// Round 15
// 40.262 us; speedup vs baseline: 1.0943x; 1.0943x over previous
//
#include <hip/hip_runtime.h>

typedef __bf16 bf16_t;
typedef __bf16 bf16x4 __attribute__((ext_vector_type(4)));
typedef __bf16 bf16x8 __attribute__((ext_vector_type(8)));
typedef float  f32x4  __attribute__((ext_vector_type(4)));

#define B_SZ  16
#define L_SEQ 2048
#define D_H   64
#define QB    64
#define KB    64

// softmax is over (S/8); fold log2(e)/8 into Q so MFMA output is in log2 units
#define QSCALE 0.18033688011112043f

// ws: Opart[2048 slots][64*64] f32 (32 MB) | MLb[2048][128] f32 (m:0..63, l:64..127)
#define OPART_FL ((size_t)2048 * QB * D_H)
#define ML_FL    ((size_t)2048 * 128)

// ---------------- main kernel: 4-wave KB=64 engine, 4 blocks/CU (4 waves/SIMD) ----------------
// pair p (0..15): tileL qt=31-p (nktL = 32-p chunks), tileS qt=p (nktS = p+1), total 33.
// role r takes positions [r*8, r*8+total) of the tileL-then-tileS chunk sequence ({8,8,8,9}).
// Every role writes partials (m,l,O) for both tile types (empty -> m=-1e30, l=0).
__global__ __launch_bounds__(256, 4)
void attn_split_kernel(const float* __restrict__ Qg, const float* __restrict__ Kg,
                       const float* __restrict__ Vg,
                       float* __restrict__ Opart, float* __restrict__ MLb)
{
    const int lin  = blockIdx.x;            // 0..1023
    const int xcd  = lin & 7;
    const int b    = xcd * 2 + ((lin >> 3) & 1);
    const int p    = (lin >> 4) & 15;
    const int role = (lin >> 8) & 3;        // 4 roles of a pair co-resident on one CU
    const int pair = b * 16 + p;

    const int nktL = 32 - p;                // chunks of qtL = 31-p
    const int posStart = role * 8;
    const int total    = (role == 3) ? 9 : 8;
    int cnt1 = nktL - posStart;
    cnt1 = cnt1 < 0 ? 0 : (cnt1 > total ? total : cnt1);   // this role's tileL iters

    const int slotL = (pair * 4 + role) * 2;
    const int slotS = slotL + 1;

    const int tid  = threadIdx.x;
    const int wave = tid >> 6;              // 0..3
    const int lane = tid & 63;
    const int lg   = lane >> 4;
    const int lc   = lane & 15;
    const int lc7  = lc & 7;

    __shared__ __align__(16) bf16_t K_lds[2][KB * D_H];    // 16 KB (XOR-swizzled rows of 64)
    __shared__ __align__(16) bf16_t Vt_lds[2][D_H * KB];   // 16 KB (transposed+phi+swizzled)

    const size_t bbase = (size_t)b * L_SEQ * D_H;

    // ---- staging maps (256 threads, KB=64 chunk = 64 rows) ----
    const int vkb  = tid & 15;              // k-block (4 rows) 0..15
    const int vdg  = tid >> 4;              // d-block 0..15
    const int vpos = ((vkb >> 3) << 5) + ((vkb & 3) << 3) + (((vkb >> 2) & 1) << 2);

    f32x4 kreg[4], vreg[4];

    auto issueK = [&](int kt) {
        const int kb = kt * KB;
#pragma unroll
        for (int i = 0; i < 2; ++i) {
            const int u = i * 256 + tid;    // bf16x8-chunk id 0..511
            const int r = u >> 3, ch = u & 7;
            const float* ptr = Kg + bbase + (size_t)(kb + r) * D_H + ch * 8;
            kreg[2 * i]     = *reinterpret_cast<const f32x4*>(ptr);
            kreg[2 * i + 1] = *reinterpret_cast<const f32x4*>(ptr + 4);
        }
    };
    auto issueV = [&](int kt) {
        const int kb = kt * KB;
#pragma unroll
        for (int i = 0; i < 4; ++i)
            vreg[i] = *reinterpret_cast<const f32x4*>(
                Vg + bbase + (size_t)(kb + vkb * 4 + i) * D_H + vdg * 4);
    };
    auto writeK = [&](int buf) {
#pragma unroll
        for (int i = 0; i < 2; ++i) {
            const int u = i * 256 + tid;
            const int r = u >> 3, ch = u & 7;
            bf16x8 kk;
#pragma unroll
            for (int j = 0; j < 4; ++j) { kk[j] = (bf16_t)kreg[2 * i][j]; kk[4 + j] = (bf16_t)kreg[2 * i + 1][j]; }
            *reinterpret_cast<bf16x8*>(&K_lds[buf][r * 64 + ((ch ^ (r & 7)) << 3)]) = kk;
        }
    };
    auto writeV = [&](int buf) {
#pragma unroll
        for (int j = 0; j < 4; ++j) {
            const int d = vdg * 4 + j;
            bf16x4 cj = { (bf16_t)vreg[0][j], (bf16_t)vreg[1][j],
                          (bf16_t)vreg[2][j], (bf16_t)vreg[3][j] };
            const int hw = d * 64 + (((vpos >> 3) ^ (d & 7)) << 3) + (vpos & 7);
            *reinterpret_cast<bf16x4*>(&Vt_lds[buf][hw]) = cj;
        }
    };

    bf16x8 qa[2];
    int qrow;
    auto loadQ = [&](int qt_) {
        qrow = qt_ * QB + wave * 16 + lc;
#pragma unroll
        for (int h = 0; h < 2; ++h) {
            const float* qp = Qg + bbase + (size_t)qrow * D_H + h * 32 + lg * 8;
            const f32x4 f0 = *reinterpret_cast<const f32x4*>(qp);
            const f32x4 f1 = *reinterpret_cast<const f32x4*>(qp + 4);
            bf16x8 a;
#pragma unroll
            for (int j = 0; j < 4; ++j) { a[j] = (bf16_t)(f0[j] * QSCALE); a[4 + j] = (bf16_t)(f1[j] * QSCALE); }
            qa[h] = a;
        }
    };

    loadQ(cnt1 > 0 ? (31 - p) : p);

    f32x4 o[4];
#pragma unroll
    for (int dt = 0; dt < 4; ++dt) o[dt] = (f32x4){0.f, 0.f, 0.f, 0.f};
    float m = -1e30f, l = 0.f;              // per-lane l partial in frame m

    auto writePartial = [&](int slot) {
        float lr = l;
        lr += __shfl_xor(lr, 16);
        lr += __shfl_xor(lr, 32);
        float* ob = Opart + (size_t)slot * (QB * D_H);
        const int qL = wave * 16 + lc;      // 0..63
#pragma unroll
        for (int dt = 0; dt < 4; ++dt)
            *reinterpret_cast<f32x4*>(&ob[qL * 64 + dt * 16 + lg * 4]) = o[dt];
        if (lg == 0) { MLb[slot * 128 + qL] = m; MLb[slot * 128 + 64 + qL] = lr; }
    };
    auto writeEmpty = [&](int slot) {
        const int qL = wave * 16 + lc;
        if (lg == 0) { MLb[slot * 128 + qL] = -1e30f; MLb[slot * 128 + 64 + qL] = 0.f; }
    };

    auto seqKt = [&](int j) { const int pos = posStart + j; return pos < nktL ? pos : pos - nktL; };

    issueK(seqKt(0)); issueV(seqKt(0)); writeK(0); writeV(0);
    __syncthreads();
    int cur = 0;

    for (int j = 0; j < total; ++j) {
        if (cnt1 > 0 && cnt1 < total && j == cnt1) {
            // straddler: commit tileL partial, switch to tileS
            writePartial(slotL);
            loadQ(p);
#pragma unroll
            for (int dt = 0; dt < 4; ++dt) o[dt] = (f32x4){0.f, 0.f, 0.f, 0.f};
            m = -1e30f; l = 0.f;
        }
        const int pos = posStart + j;
        const int kt  = pos < nktL ? pos : pos - nktL;
        const int kb0 = kt * KB;
        const bool more = (j + 1 < total);
        if (more) issueK(seqKt(j + 1));

        // ---- S^T = K Q^T (log2 units): sc[n][r] = S[k=kb0+n*16+lg*4+r][q=qrow] ----
        f32x4 sc[4];
        __builtin_amdgcn_s_setprio(1);
#pragma unroll
        for (int n = 0; n < 4; ++n) {
            f32x4 acc = (f32x4){0.f, 0.f, 0.f, 0.f};
#pragma unroll
            for (int h = 0; h < 2; ++h) {
                const int hw = (n * 16 + lc) * 64 + ((((h << 2) | lg) ^ lc7) << 3);
                const bf16x8 kkb = *reinterpret_cast<const bf16x8*>(&K_lds[cur][hw]);
                acc = __builtin_amdgcn_mfma_f32_16x16x32_bf16(kkb, qa[h], acc, 0, 0, 0);
            }
            sc[n] = acc;
        }
        __builtin_amdgcn_s_setprio(0);
        if (more) issueV(seqKt(j + 1));

        const bool diag = (pos == nktL - 1) || (pos == 32);   // diagonal chunk of L or S
        if (diag) {
#pragma unroll
            for (int n = 0; n < 4; ++n)
#pragma unroll
                for (int r = 0; r < 4; ++r)
                    if (kb0 + n * 16 + lg * 4 + r > qrow) sc[n][r] = -1e30f;
        }

        // ---- defer-max online softmax (per-lane; cross-lane only on slow path) ----
        float mxp = fmaxf(fmaxf(sc[0][0], sc[0][1]), fmaxf(sc[0][2], sc[0][3]));
#pragma unroll
        for (int n = 1; n < 4; ++n)
            mxp = fmaxf(mxp, fmaxf(fmaxf(sc[n][0], sc[n][1]), fmaxf(sc[n][2], sc[n][3])));
        if (!__all(mxp <= m + 8.0f)) {
            float mx = mxp;
            mx = fmaxf(mx, __shfl_xor(mx, 16));
            mx = fmaxf(mx, __shfl_xor(mx, 32));
            const float mn = fmaxf(m, mx);
            const float alpha = exp2f(m - mn);
            m = mn;
            l *= alpha;
#pragma unroll
            for (int dt = 0; dt < 4; ++dt)
#pragma unroll
                for (int r = 0; r < 4; ++r) o[dt][r] *= alpha;
        }
        // P packed directly into the PV B-operand layout (phi-permuted V^T)
        bf16x8 w[2];
        float rs = 0.f;
#pragma unroll
        for (int n = 0; n < 4; ++n) {
            const float p0 = exp2f(sc[n][0] - m), p1 = exp2f(sc[n][1] - m);
            const float p2 = exp2f(sc[n][2] - m), p3 = exp2f(sc[n][3] - m);
            rs += (p0 + p1) + (p2 + p3);
            const int wi = n >> 1, off = (n & 1) * 4;
            w[wi][off + 0] = (bf16_t)p0; w[wi][off + 1] = (bf16_t)p1;
            w[wi][off + 2] = (bf16_t)p2; w[wi][off + 3] = (bf16_t)p3;
        }
        l += rs;

        if (more) writeK(cur ^ 1);          // free kreg before PV

        // ---- O^T += V^T P : P straight from registers, V^T from swizzled LDS ----
        __builtin_amdgcn_s_setprio(1);
#pragma unroll
        for (int ks = 0; ks < 2; ++ks) {
#pragma unroll
            for (int dt = 0; dt < 4; ++dt) {
                const int hw = (dt * 16 + lc) * 64 + ((((ks << 2) | lg) ^ lc7) << 3);
                const bf16x8 vb = *reinterpret_cast<const bf16x8*>(&Vt_lds[cur][hw]);
                o[dt] = __builtin_amdgcn_mfma_f32_16x16x32_bf16(vb, w[ks], o[dt], 0, 0, 0);
            }
        }
        __builtin_amdgcn_s_setprio(0);

        if (more) writeV(cur ^ 1);
        __syncthreads();
        cur ^= 1;
    }

    // ---- epilogue: commit final partial; mark untouched tile type empty ----
    if (cnt1 == total) {                    // pure tileL role
        writePartial(slotL);
        writeEmpty(slotS);
    } else if (cnt1 == 0) {                 // pure tileS role
        writeEmpty(slotL);
        writePartial(slotS);
    } else {                                // straddler: tileL written at switch
        writePartial(slotS);
    }
}

// ---------------- merge: combine up to 4 partials per (pair, tile-type) ----------------
__global__ __launch_bounds__(256)
void merge4_kernel(const float* __restrict__ Opart, const float* __restrict__ MLb,
                   float* __restrict__ Og)
{
    const int blk  = blockIdx.x;            // 0..511 (low bits track producer XCD)
    const int xcd  = blk & 7;
    const int b    = xcd * 2 + ((blk >> 3) & 1);
    const int p    = (blk >> 4) & 15;
    const int type = (blk >> 8) & 1;        // 0 = tileL, 1 = tileS
    const int pair = b * 16 + p;
    const int qt   = type ? p : (31 - p);

    const int t  = threadIdx.x;
    const int q  = t >> 2;                  // 0..63
    const int dc = (t & 3) * 16;            // 0,16,32,48

    float mv[4], lv[4];
#pragma unroll
    for (int r = 0; r < 4; ++r) {
        const int slot = (pair * 4 + r) * 2 + type;
        mv[r] = MLb[slot * 128 + q];
        lv[r] = MLb[slot * 128 + 64 + q];
    }
    const float mt = fmaxf(fmaxf(mv[0], mv[1]), fmaxf(mv[2], mv[3]));
    float wv[4], den = 0.f;
#pragma unroll
    for (int r = 0; r < 4; ++r) { wv[r] = exp2f(mv[r] - mt); den += lv[r] * wv[r]; }
    const float inv = 1.0f / den;

    f32x4 acc[4];
#pragma unroll
    for (int i = 0; i < 4; ++i) acc[i] = (f32x4){0.f, 0.f, 0.f, 0.f};
#pragma unroll
    for (int r = 0; r < 4; ++r) {
        if (lv[r] != 0.0f) {                // empty slots never read
            const float* orp = Opart + (size_t)((pair * 4 + r) * 2 + type) * (QB * D_H) + q * 64 + dc;
#pragma unroll
            for (int i = 0; i < 4; ++i) {
                const f32x4 v = *reinterpret_cast<const f32x4*>(orp + i * 4);
#pragma unroll
                for (int k2 = 0; k2 < 4; ++k2) acc[i][k2] += v[k2] * wv[r];
            }
        }
    }
    float* og = Og + (size_t)b * L_SEQ * D_H + (size_t)(qt * QB + q) * D_H + dc;
#pragma unroll
    for (int i = 0; i < 4; ++i) {
        f32x4 rr;
#pragma unroll
        for (int k2 = 0; k2 < 4; ++k2) rr[k2] = acc[i][k2] * inv;
        *reinterpret_cast<f32x4*>(og + i * 4) = rr;
    }
}

// ---------------- fallback (no-ws path, round-6 kernel) ----------------
__global__ __launch_bounds__(256, 2)
void attn_fwd_fb(const float* __restrict__ Qg, const float* __restrict__ Kg,
                 const float* __restrict__ Vg, float* __restrict__ Og)
{
    const int lin  = blockIdx.x;
    const int xcd  = lin & 7;
    const int slot = lin >> 3;
    const int half = slot >> 5;
    const int qi   = slot & 31;
    const int b    = xcd * 2 + half;
    const int qt   = half ? qi : (31 - qi);

    const int tid  = threadIdx.x;
    const int lane = tid & 63;
    const int lg   = lane >> 4;
    const int lc   = lane & 15;
    const int lc7  = lc & 7;

    __shared__ __align__(16) bf16_t K_lds[2][128 * 64];
    __shared__ __align__(16) bf16_t Vt_lds[2][64 * 128];

    const size_t bbase = (size_t)b * L_SEQ * D_H;
    const int qrow = qt * 64 + (tid >> 6) * 16 + lc;
    bf16x8 qa[2];
#pragma unroll
    for (int h = 0; h < 2; ++h) {
        const float* qp = Qg + bbase + (size_t)qrow * D_H + h * 32 + lg * 8;
        const f32x4 f0 = *reinterpret_cast<const f32x4*>(qp);
        const f32x4 f1 = *reinterpret_cast<const f32x4*>(qp + 4);
        bf16x8 a;
#pragma unroll
        for (int j = 0; j < 4; ++j) { a[j] = (bf16_t)(f0[j] * QSCALE); a[4 + j] = (bf16_t)(f1[j] * QSCALE); }
        qa[h] = a;
    }
    f32x4 o[4];
#pragma unroll
    for (int dt = 0; dt < 4; ++dt) o[dt] = (f32x4){0.f, 0.f, 0.f, 0.f};
    float m = -1e30f, l = 0.f;
    const int nkt = (qt + 2) >> 1;
    const int vkb  = tid & 31;
    const int vdg  = tid >> 5;
    const int vpos = ((vkb >> 3) << 5) + ((vkb & 3) << 3) + (((vkb >> 2) & 1) << 2);
    f32x4 kreg[8], vreg[8];

    auto issueK = [&](int kt) {
        const int kbase = kt * 128;
#pragma unroll
        for (int i = 0; i < 4; ++i) {
            const int u = i * 256 + tid;
            const int r = u >> 3, ch = u & 7;
            const float* p = Kg + bbase + (size_t)(kbase + r) * D_H + ch * 8;
            kreg[2 * i]     = *reinterpret_cast<const f32x4*>(p);
            kreg[2 * i + 1] = *reinterpret_cast<const f32x4*>(p + 4);
        }
    };
    auto issueV = [&](int kt) {
        const int kbase = kt * 128;
#pragma unroll
        for (int d2 = 0; d2 < 2; ++d2)
#pragma unroll
            for (int i = 0; i < 4; ++i)
                vreg[d2 * 4 + i] = *reinterpret_cast<const f32x4*>(
                    Vg + bbase + (size_t)(kbase + vkb * 4 + i) * D_H + (vdg + d2 * 8) * 4);
    };
    auto writeK = [&](int buf) {
#pragma unroll
        for (int i = 0; i < 4; ++i) {
            const int u = i * 256 + tid;
            const int r = u >> 3, ch = u & 7;
            bf16x8 kk;
#pragma unroll
            for (int j = 0; j < 4; ++j) { kk[j] = (bf16_t)kreg[2 * i][j]; kk[4 + j] = (bf16_t)kreg[2 * i + 1][j]; }
            *reinterpret_cast<bf16x8*>(&K_lds[buf][r * 64 + ((ch ^ (r & 7)) << 3)]) = kk;
        }
    };
    auto writeV = [&](int buf) {
#pragma unroll
        for (int d2 = 0; d2 < 2; ++d2) {
            const int db = vdg + d2 * 8;
#pragma unroll
            for (int j = 0; j < 4; ++j) {
                const int d = db * 4 + j;
                bf16x4 cj = { (bf16_t)vreg[d2 * 4 + 0][j], (bf16_t)vreg[d2 * 4 + 1][j],
                              (bf16_t)vreg[d2 * 4 + 2][j], (bf16_t)vreg[d2 * 4 + 3][j] };
                const int hw = d * 128 + (((vpos >> 3) ^ (d & 7)) << 3) + (vpos & 7);
                *reinterpret_cast<bf16x4*>(&Vt_lds[buf][hw]) = cj;
            }
        }
    };

    issueK(0); issueV(0); writeK(0); writeV(0);
    __syncthreads();
    int cur = 0;
    for (int kt = 0; kt < nkt; ++kt) {
        const bool last = (kt == nkt - 1);
        const int kbase = kt * 128;
        if (!last) issueK(kt + 1);
        f32x4 sc[8];
#pragma unroll
        for (int n = 0; n < 8; ++n) {
            f32x4 acc = (f32x4){0.f, 0.f, 0.f, 0.f};
#pragma unroll
            for (int h = 0; h < 2; ++h) {
                const int hw = (n * 16 + lc) * 64 + ((((h << 2) | lg) ^ lc7) << 3);
                const bf16x8 kkb = *reinterpret_cast<const bf16x8*>(&K_lds[cur][hw]);
                acc = __builtin_amdgcn_mfma_f32_16x16x32_bf16(kkb, qa[h], acc, 0, 0, 0);
            }
            sc[n] = acc;
        }
        if (!last) issueV(kt + 1);
        if (last) {
#pragma unroll
            for (int n = 0; n < 8; ++n)
#pragma unroll
                for (int r = 0; r < 4; ++r)
                    if (kbase + n * 16 + lg * 4 + r > qrow) sc[n][r] = -1e30f;
        }
        float mxp = fmaxf(fmaxf(sc[0][0], sc[0][1]), fmaxf(sc[0][2], sc[0][3]));
#pragma unroll
        for (int n = 1; n < 8; ++n)
            mxp = fmaxf(mxp, fmaxf(fmaxf(sc[n][0], sc[n][1]), fmaxf(sc[n][2], sc[n][3])));
        if (!__all(mxp <= m + 8.0f)) {
            float mx = mxp;
            mx = fmaxf(mx, __shfl_xor(mx, 16));
            mx = fmaxf(mx, __shfl_xor(mx, 32));
            const float mn = fmaxf(m, mx);
            const float alpha = exp2f(m - mn);
            m = mn; l *= alpha;
#pragma unroll
            for (int dt = 0; dt < 4; ++dt)
#pragma unroll
                for (int r = 0; r < 4; ++r) o[dt][r] *= alpha;
        }
        bf16x8 w[4];
        float rs = 0.f;
#pragma unroll
        for (int n = 0; n < 8; ++n) {
            const float p0 = exp2f(sc[n][0] - m), p1 = exp2f(sc[n][1] - m);
            const float p2 = exp2f(sc[n][2] - m), p3 = exp2f(sc[n][3] - m);
            rs += (p0 + p1) + (p2 + p3);
            const int wi = n >> 1, off = (n & 1) * 4;
            w[wi][off + 0] = (bf16_t)p0; w[wi][off + 1] = (bf16_t)p1;
            w[wi][off + 2] = (bf16_t)p2; w[wi][off + 3] = (bf16_t)p3;
        }
        l += rs;
        if (!last) writeK(cur ^ 1);
#pragma unroll
        for (int ks = 0; ks < 4; ++ks) {
#pragma unroll
            for (int dt = 0; dt < 4; ++dt) {
                const int hw = (dt * 16 + lc) * 128 + ((((ks << 2) | lg) ^ lc7) << 3);
                const bf16x8 vb = *reinterpret_cast<const bf16x8*>(&Vt_lds[cur][hw]);
                o[dt] = __builtin_amdgcn_mfma_f32_16x16x32_bf16(vb, w[ks], o[dt], 0, 0, 0);
            }
        }
        if (!last) writeV(cur ^ 1);
        __syncthreads();
        cur ^= 1;
    }
    float lr = l;
    lr += __shfl_xor(lr, 16);
    lr += __shfl_xor(lr, 32);
    const float inv = 1.0f / lr;
#pragma unroll
    for (int dt = 0; dt < 4; ++dt) {
        f32x4 val = { o[dt][0] * inv, o[dt][1] * inv, o[dt][2] * inv, o[dt][3] * inv };
        *reinterpret_cast<f32x4*>(Og + bbase + (size_t)qrow * D_H + dt * 16 + lg * 4) = val;
    }
}

extern "C" void kernel_launch(void* const* d_in, const int* in_sizes, int n_in,
                              void* d_out, int out_size, void* d_ws, size_t ws_size,
                              hipStream_t stream)
{
    const float* Q = (const float*)d_in[0];
    const float* K = (const float*)d_in[1];
    const float* V = (const float*)d_in[2];
    float* O = (float*)d_out;

    const size_t need = (OPART_FL + ML_FL) * sizeof(float);   // ~33.5 MB
    if (ws_size >= need) {
        float* Opart = (float*)d_ws;
        float* MLb   = Opart + OPART_FL;
        attn_split_kernel<<<dim3(1024), dim3(256), 0, stream>>>(Q, K, V, Opart, MLb);
        merge4_kernel<<<dim3(512), dim3(256), 0, stream>>>(Opart, MLb, O);
    } else {
        attn_fwd_fb<<<dim3(512), dim3(256), 0, stream>>>(Q, K, V, O);
    }
}